// Round 1
// baseline (596.809 us; speedup 1.0000x reference)
//
#include <hip/hip_runtime.h>

#define SEQ 600
#define PP 6
#define TOUT 594        // SEQ - PP
#define NF4 150         // float4s per row
#define NF4P 152        // padded (8 zero floats)

typedef float v4f __attribute__((ext_vector_type(4)));

// ---- DPP wave-64 sum (canonical gfx9 sequence, VALU-only) ----
template<int CTRL>
__device__ __forceinline__ float dpp_mov(float v) {
    return __int_as_float(__builtin_amdgcn_update_dpp(
        0, __float_as_int(v), CTRL, 0xF, 0xF, true));   // bound_ctrl: zero-fill
}
__device__ __forceinline__ float wave_sum(float v) {
    v += dpp_mov<0x111>(v);   // row_shr:1
    v += dpp_mov<0x112>(v);   // row_shr:2
    v += dpp_mov<0x114>(v);   // row_shr:4
    v += dpp_mov<0x118>(v);   // row_shr:8
    v += dpp_mov<0x142>(v);   // row_bcast:15
    v += dpp_mov<0x143>(v);   // row_bcast:31
    return __int_as_float(__builtin_amdgcn_readlane(__float_as_int(v), 63));
}

// ============================================================================
// Kernel A: per-row AR(6) solve + x_hat + extras + stash w into workspace.
// One wave per row; block = 256 = 4 rows; grid = N/4. High VGPR is OK here:
// the heavy streaming output (coeffs, 472 MB) moved to the low-VGPR kernel B.
// ============================================================================
__global__ __launch_bounds__(256) void ar_solve_kernel(
    const float* __restrict__ x,
    float* __restrict__ wbuf,     // N*8 floats: {w1..w6, 0, 0} per row
    float* __restrict__ extra,    // p_logits (N*5) then p_hard (N)
    float* __restrict__ x_hat,
    int N)
{
    __shared__ __align__(16) v4f sxr[4][NF4P];

    const int wave = threadIdx.x >> 6;
    const int lane = threadIdx.x & 63;
    const int row  = (blockIdx.x << 2) + wave;

    v4f* s4 = sxr[wave];

    // ---- stage row into LDS (nontemporal float4 loads, coalesced) + zero pad ----
    {
        const v4f* xr = reinterpret_cast<const v4f*>(x + (size_t)row * SEQ);
        v4f r0 = __builtin_nontemporal_load(xr + lane);
        v4f r1 = __builtin_nontemporal_load(xr + lane + 64);
        v4f r2;
        const int m2 = lane + 128;
        if (m2 < NF4) r2 = __builtin_nontemporal_load(xr + m2);
        s4[lane] = r0;
        s4[lane + 64] = r1;
        if (m2 < NF4) s4[m2] = r2;
        if (lane < 2) { v4f z = {0.f, 0.f, 0.f, 0.f}; s4[NF4 + lane] = z; }
    }
    __syncthreads();

    // ---- Q[d] = sum_i x[i]*x[i+d] (zero-padded), S = sum x; b128 windows ----
    float S = 0.f;
    float Q[7] = {0.f, 0.f, 0.f, 0.f, 0.f, 0.f, 0.f};
    #pragma unroll
    for (int k = 0; k < 3; ++k) {
        const int m = lane + 64 * k;
        if (m < NF4) {
            v4f a = s4[m], b = s4[m + 1], c = s4[m + 2];
            float W[12] = {a.x, a.y, a.z, a.w, b.x, b.y, b.z, b.w,
                           c.x, c.y, c.z, c.w};
            #pragma unroll
            for (int cc = 0; cc < 4; ++cc) {
                S += W[cc];
                #pragma unroll
                for (int d = 0; d < 7; ++d) Q[d] += W[cc] * W[cc + d];
            }
        }
    }
    // VALU-only wave reduction (replaces 48 ds_swizzle, ~700-cyc chain)
    S = wave_sum(S);
    #pragma unroll
    for (int d = 0; d < 7; ++d) Q[d] = wave_sum(Q[d]);

    // ---- boundary values via 4 uniform b128 reads (pads are known zero) ----
    float low[8], hig[8];
    {
        v4f e0 = s4[0], e1 = s4[1];
        v4f t0 = s4[148], t1 = s4[149];
        low[0]=e0.x; low[1]=e0.y; low[2]=e0.z; low[3]=e0.w;
        low[4]=e1.x; low[5]=e1.y; low[6]=e1.z; low[7]=e1.w;
        hig[0]=t0.x; hig[1]=t0.y; hig[2]=t0.z; hig[3]=t0.w;   // sx[592..595]
        hig[4]=t1.x; hig[5]=t1.y; hig[6]=t1.z; hig[7]=t1.w;   // sx[596..599]
    }
    float pre[8], suf[8];
    pre[0] = 0.f; suf[0] = 0.f;
    #pragma unroll
    for (int c = 1; c < 8; ++c) {
        pre[c] = pre[c - 1] + low[c - 1];
        suf[c] = suf[c - 1] + hig[8 - c];      // sx[600-c]
    }

    // ---- normal equations G (7x7) and rhs ----
    float M[7][7];
    float rhs[7];
    M[0][0] = (float)TOUT;
    #pragma unroll
    for (int k = 0; k < 6; ++k) {
        float v = S - pre[5 - k] - suf[k + 1];
        M[k + 1][0] = v; M[0][k + 1] = v;
    }
    #pragma unroll
    for (int k = 0; k < 6; ++k) {
        #pragma unroll
        for (int l = k; l < 6; ++l) {
            const int a = 5 - l, d = l - k;
            float head = 0.f;
            #pragma unroll
            for (int i = 0; i < a; ++i) head += low[i] * low[i + d];
            float tail = 0.f;
            #pragma unroll
            for (int i = a + TOUT; i < SEQ; ++i)
                if (i + d < SEQ) tail += hig[i - 592] * hig[i + d - 592];
            float v = Q[d] - head - tail;
            M[l + 1][k + 1] = v; M[k + 1][l + 1] = v;
        }
    }
    rhs[0] = S - pre[6];
    #pragma unroll
    for (int k = 0; k < 6; ++k) {
        const int a = 5 - k, d = k + 1;
        float head = 0.f;
        #pragma unroll
        for (int i = 0; i < a; ++i) head += low[i] * low[i + d];
        float tail = 0.f;
        #pragma unroll
        for (int i = a + TOUT; i < SEQ; ++i)
            if (i + d < SEQ) tail += hig[i - 592] * hig[i + d - 592];
        rhs[k + 1] = Q[d] - head - tail;
    }

    // ---- Cholesky (SPD) with rcp-based inverse diag; redundant per-lane ----
    float invd[7];
    #pragma unroll
    for (int j = 0; j < 7; ++j) {
        float s = M[j][j];
        #pragma unroll
        for (int m = 0; m < j; ++m) s -= M[j][m] * M[j][m];
        float ljj = sqrtf(s);
        M[j][j] = ljj;
        float inv = __builtin_amdgcn_rcpf(ljj);
        invd[j] = inv;
        #pragma unroll
        for (int i2 = j + 1; i2 < 7; ++i2) {
            float s2 = M[i2][j];
            #pragma unroll
            for (int m = 0; m < j; ++m) s2 -= M[i2][m] * M[j][m];
            M[i2][j] = s2 * inv;
        }
    }
    float w[7], z[7];
    #pragma unroll
    for (int i2 = 0; i2 < 7; ++i2) {
        float s = rhs[i2];
        #pragma unroll
        for (int m = 0; m < i2; ++m) s -= M[i2][m] * z[m];
        z[i2] = s * invd[i2];
    }
    #pragma unroll
    for (int i2 = 6; i2 >= 0; --i2) {
        float s = z[i2];
        #pragma unroll
        for (int m = i2 + 1; m < 7; ++m) s -= M[m][i2] * w[m];
        w[i2] = s * invd[i2];
    }

    // ---- stash w for the coeffs-writer kernel (8 floats/row, 1 MB total) ----
    if (lane == 0) {
        v4f wlo = {w[1], w[2], w[3], w[4]};
        v4f whi = {w[5], w[6], 0.f, 0.f};
        v4f* wsr = reinterpret_cast<v4f*>(wbuf + (size_t)row * 8);
        wsr[0] = wlo;
        wsr[1] = whi;
    }

    // ---- x_hat: b128 windows; t<6 -> 0 (nontemporal streaming stores) ----
    {
        v4f* xh4 = reinterpret_cast<v4f*>(x_hat + (size_t)row * SEQ);
        #pragma unroll
        for (int k = 0; k < 3; ++k) {
            const int m = lane + 64 * k;
            if (m < NF4) {
                v4f v;
                if (m == 0) {
                    v4f zz = {0.f, 0.f, 0.f, 0.f};
                    v = zz;
                } else {
                    const int mm2 = (m >= 2) ? (m - 2) : 0;   // clamp; W[0..3] unused when m==1
                    v4f ra = s4[mm2], rb = s4[m - 1], rc = s4[m];
                    float W[12] = {ra.x, ra.y, ra.z, ra.w, rb.x, rb.y, rb.z, rb.w,
                                   rc.x, rc.y, rc.z, rc.w};   // W[j] = sx[4m-8+j]
                    float p[4];
                    #pragma unroll
                    for (int c = 0; c < 4; ++c) {
                        float s = w[0];
                        #pragma unroll
                        for (int kk = 1; kk <= 6; ++kk) s += w[kk] * W[8 + c - kk];
                        p[c] = s;
                    }
                    if (m == 1) { p[0] = 0.f; p[1] = 0.f; }   // e=4,5 < PP
                    v.x = p[0]; v.y = p[1]; v.z = p[2]; v.w = p[3];
                }
                __builtin_nontemporal_store(v, xh4 + m);
            }
        }
    }

    // ---- p_logits / p_hard zeros ----
    if (lane < 5) extra[(size_t)5 * row + lane] = 0.f;
    if (lane == 5) extra[(size_t)5 * N + row] = 0.f;
}

// ============================================================================
// Kernel B: pure streaming coeffs writer. ~30 VGPR -> 8 waves/SIMD occupancy.
// Reads 8 floats/row (L2-resident, written by kernel A on same stream),
// replays the verified per-lane rotated 12-float pattern, nontemporal stores.
// ============================================================================
__global__ __launch_bounds__(256) void coeff_write_kernel(
    const float* __restrict__ wbuf,
    float* __restrict__ coeffs)
{
    const int wave = threadIdx.x >> 6;
    const int lane = threadIdx.x & 63;
    const int row  = (blockIdx.x << 2) + wave;

    const v4f* wr = reinterpret_cast<const v4f*>(wbuf + (size_t)row * 8);
    const v4f wa = wr[0];                 // {w1, w2, w3, w4}
    const v4f wb = wr[1];                 // {w5, w6, 0, 0}

    const v4f P0 = {wa.x, wa.y, wa.z, wa.w};   // {w1,w2,w3,w4}
    const v4f P1 = {wb.x, wb.y, wa.x, wa.y};   // {w5,w6,w1,w2}
    const v4f P2 = {wa.z, wa.w, wb.x, wb.y};   // {w3,w4,w5,w6}
    const int r0 = lane % 3;                   // phase of float4 index i = lane
    const v4f A0 = (r0 == 0) ? P0 : ((r0 == 1) ? P1 : P2);
    const v4f A1 = (r0 == 0) ? P1 : ((r0 == 1) ? P2 : P0);
    const v4f A2 = (r0 == 0) ? P2 : ((r0 == 1) ? P0 : P1);

    v4f* crow = reinterpret_cast<v4f*>(coeffs + (size_t)row * (SEQ * PP));
    // j=0: float4 indices < 9 (flat < 36, i.e. t < 6) are zero
    v4f zz = {0.f, 0.f, 0.f, 0.f};
    __builtin_nontemporal_store((lane <= 8) ? zz : A0, crow + lane);
    #pragma unroll
    for (int j = 1; j < 14; ++j) {
        __builtin_nontemporal_store(
            (j % 3 == 0) ? A0 : ((j % 3 == 1) ? A1 : A2), crow + lane + 64 * j);
    }
    if (lane < 4) __builtin_nontemporal_store(A2, crow + lane + 64 * 14); // i=896..899, phase 2
}

extern "C" void kernel_launch(void* const* d_in, const int* in_sizes, int n_in,
                              void* d_out, int out_size, void* d_ws, size_t ws_size,
                              hipStream_t stream) {
    const float* x = (const float*)d_in[0];
    const int N = in_sizes[0] / SEQ;           // 32768

    float* out    = (float*)d_out;
    float* coeffs = out;                                 // N*600*6
    float* extra  = out + (size_t)N * SEQ * PP;          // p_logits (N*5) + p_hard (N)
    float* x_hat  = extra + (size_t)N * 6;               // N*600

    float* wbuf = (float*)d_ws;                          // N*8 floats = 1 MB

    ar_solve_kernel<<<dim3(N / 4), dim3(256), 0, stream>>>(x, wbuf, extra, x_hat, N);
    coeff_write_kernel<<<dim3(N / 4), dim3(256), 0, stream>>>(wbuf, coeffs);
}

// Round 2
// 594.565 us; speedup vs baseline: 1.0038x; 1.0038x over previous
//
#include <hip/hip_runtime.h>

#define SEQ 600
#define PP 6
#define TOUT 594        // SEQ - PP
#define NF4 150         // float4s per row
#define NF4P 152        // padded (8 zero floats)

typedef float v4f __attribute__((ext_vector_type(4)));

// ---- DPP wave-64 sum (canonical gfx9 sequence, VALU-only) ----
template<int CTRL>
__device__ __forceinline__ float dpp_mov(float v) {
    return __int_as_float(__builtin_amdgcn_update_dpp(
        0, __float_as_int(v), CTRL, 0xF, 0xF, true));   // bound_ctrl: zero-fill
}
__device__ __forceinline__ float wave_sum(float v) {
    v += dpp_mov<0x111>(v);   // row_shr:1
    v += dpp_mov<0x112>(v);   // row_shr:2
    v += dpp_mov<0x114>(v);   // row_shr:4
    v += dpp_mov<0x118>(v);   // row_shr:8
    v += dpp_mov<0x142>(v);   // row_bcast:15
    v += dpp_mov<0x143>(v);   // row_bcast:31
    return __int_as_float(__builtin_amdgcn_readlane(__float_as_int(v), 63));
}

// ============================================================================
// Kernel A: per-row AR(6) solve + x_hat + extras + stash w into workspace.
// One wave per row; block = 256 = 4 rows; grid = N/4.
// __launch_bounds__(256,4): 4 waves/EU min -> VGPR capped at 128 (occupancy
// probe; heavy streaming output lives in kernel B).
// ============================================================================
__global__ __launch_bounds__(256, 4) void ar_solve_kernel(
    const float* __restrict__ x,
    float* __restrict__ wbuf,     // N*8 floats: {w1..w6, 0, 0} per row
    float* __restrict__ extra,    // p_logits (N*5) then p_hard (N)
    float* __restrict__ x_hat,
    int N)
{
    __shared__ __align__(16) v4f sxr[4][NF4P];

    const int wave = threadIdx.x >> 6;
    const int lane = threadIdx.x & 63;
    const int row  = (blockIdx.x << 2) + wave;

    v4f* s4 = sxr[wave];

    // ---- stage row into LDS (nontemporal float4 loads, coalesced) + zero pad ----
    {
        const v4f* xr = reinterpret_cast<const v4f*>(x + (size_t)row * SEQ);
        v4f r0 = __builtin_nontemporal_load(xr + lane);
        v4f r1 = __builtin_nontemporal_load(xr + lane + 64);
        v4f r2;
        const int m2 = lane + 128;
        if (m2 < NF4) r2 = __builtin_nontemporal_load(xr + m2);
        s4[lane] = r0;
        s4[lane + 64] = r1;
        if (m2 < NF4) s4[m2] = r2;
        if (lane < 2) { v4f z = {0.f, 0.f, 0.f, 0.f}; s4[NF4 + lane] = z; }
    }
    __syncthreads();

    // ---- Q[d] = sum_i x[i]*x[i+d] (zero-padded), S = sum x; b128 windows ----
    float S = 0.f;
    float Q[7] = {0.f, 0.f, 0.f, 0.f, 0.f, 0.f, 0.f};
    #pragma unroll
    for (int k = 0; k < 3; ++k) {
        const int m = lane + 64 * k;
        if (m < NF4) {
            v4f a = s4[m], b = s4[m + 1], c = s4[m + 2];
            float W[12] = {a.x, a.y, a.z, a.w, b.x, b.y, b.z, b.w,
                           c.x, c.y, c.z, c.w};
            #pragma unroll
            for (int cc = 0; cc < 4; ++cc) {
                S += W[cc];
                #pragma unroll
                for (int d = 0; d < 7; ++d) Q[d] += W[cc] * W[cc + d];
            }
        }
    }
    // VALU-only wave reduction
    S = wave_sum(S);
    #pragma unroll
    for (int d = 0; d < 7; ++d) Q[d] = wave_sum(Q[d]);

    // ---- boundary values via 4 uniform b128 reads (pads are known zero) ----
    float low[8], hig[8];
    {
        v4f e0 = s4[0], e1 = s4[1];
        v4f t0 = s4[148], t1 = s4[149];
        low[0]=e0.x; low[1]=e0.y; low[2]=e0.z; low[3]=e0.w;
        low[4]=e1.x; low[5]=e1.y; low[6]=e1.z; low[7]=e1.w;
        hig[0]=t0.x; hig[1]=t0.y; hig[2]=t0.z; hig[3]=t0.w;   // sx[592..595]
        hig[4]=t1.x; hig[5]=t1.y; hig[6]=t1.z; hig[7]=t1.w;   // sx[596..599]
    }
    float pre[8], suf[8];
    pre[0] = 0.f; suf[0] = 0.f;
    #pragma unroll
    for (int c = 1; c < 8; ++c) {
        pre[c] = pre[c - 1] + low[c - 1];
        suf[c] = suf[c - 1] + hig[8 - c];      // sx[600-c]
    }

    // ---- normal equations G (7x7) and rhs ----
    float M[7][7];
    float rhs[7];
    M[0][0] = (float)TOUT;
    #pragma unroll
    for (int k = 0; k < 6; ++k) {
        float v = S - pre[5 - k] - suf[k + 1];
        M[k + 1][0] = v; M[0][k + 1] = v;
    }
    #pragma unroll
    for (int k = 0; k < 6; ++k) {
        #pragma unroll
        for (int l = k; l < 6; ++l) {
            const int a = 5 - l, d = l - k;
            float head = 0.f;
            #pragma unroll
            for (int i = 0; i < a; ++i) head += low[i] * low[i + d];
            float tail = 0.f;
            #pragma unroll
            for (int i = a + TOUT; i < SEQ; ++i)
                if (i + d < SEQ) tail += hig[i - 592] * hig[i + d - 592];
            float v = Q[d] - head - tail;
            M[l + 1][k + 1] = v; M[k + 1][l + 1] = v;
        }
    }
    rhs[0] = S - pre[6];
    #pragma unroll
    for (int k = 0; k < 6; ++k) {
        const int a = 5 - k, d = k + 1;
        float head = 0.f;
        #pragma unroll
        for (int i = 0; i < a; ++i) head += low[i] * low[i + d];
        float tail = 0.f;
        #pragma unroll
        for (int i = a + TOUT; i < SEQ; ++i)
            if (i + d < SEQ) tail += hig[i - 592] * hig[i + d - 592];
        rhs[k + 1] = Q[d] - head - tail;
    }

    // ---- Cholesky (SPD) with rcp-based inverse diag; redundant per-lane ----
    float invd[7];
    #pragma unroll
    for (int j = 0; j < 7; ++j) {
        float s = M[j][j];
        #pragma unroll
        for (int m = 0; m < j; ++m) s -= M[j][m] * M[j][m];
        float ljj = sqrtf(s);
        M[j][j] = ljj;
        float inv = __builtin_amdgcn_rcpf(ljj);
        invd[j] = inv;
        #pragma unroll
        for (int i2 = j + 1; i2 < 7; ++i2) {
            float s2 = M[i2][j];
            #pragma unroll
            for (int m = 0; m < j; ++m) s2 -= M[i2][m] * M[j][m];
            M[i2][j] = s2 * inv;
        }
    }
    float w[7], z[7];
    #pragma unroll
    for (int i2 = 0; i2 < 7; ++i2) {
        float s = rhs[i2];
        #pragma unroll
        for (int m = 0; m < i2; ++m) s -= M[i2][m] * z[m];
        z[i2] = s * invd[i2];
    }
    #pragma unroll
    for (int i2 = 6; i2 >= 0; --i2) {
        float s = z[i2];
        #pragma unroll
        for (int m = i2 + 1; m < 7; ++m) s -= M[m][i2] * w[m];
        w[i2] = s * invd[i2];
    }

    // ---- stash w for the coeffs-writer kernel (8 floats/row, 1 MB total) ----
    if (lane == 0) {
        v4f wlo = {w[1], w[2], w[3], w[4]};
        v4f whi = {w[5], w[6], 0.f, 0.f};
        v4f* wsr = reinterpret_cast<v4f*>(wbuf + (size_t)row * 8);
        wsr[0] = wlo;
        wsr[1] = whi;
    }

    // ---- x_hat: b128 windows; t<6 -> 0 (nontemporal streaming stores) ----
    {
        v4f* xh4 = reinterpret_cast<v4f*>(x_hat + (size_t)row * SEQ);
        #pragma unroll
        for (int k = 0; k < 3; ++k) {
            const int m = lane + 64 * k;
            if (m < NF4) {
                v4f v;
                if (m == 0) {
                    v4f zz = {0.f, 0.f, 0.f, 0.f};
                    v = zz;
                } else {
                    const int mm2 = (m >= 2) ? (m - 2) : 0;   // clamp; W[0..3] unused when m==1
                    v4f ra = s4[mm2], rb = s4[m - 1], rc = s4[m];
                    float W[12] = {ra.x, ra.y, ra.z, ra.w, rb.x, rb.y, rb.z, rb.w,
                                   rc.x, rc.y, rc.z, rc.w};   // W[j] = sx[4m-8+j]
                    float p[4];
                    #pragma unroll
                    for (int c = 0; c < 4; ++c) {
                        float s = w[0];
                        #pragma unroll
                        for (int kk = 1; kk <= 6; ++kk) s += w[kk] * W[8 + c - kk];
                        p[c] = s;
                    }
                    if (m == 1) { p[0] = 0.f; p[1] = 0.f; }   // e=4,5 < PP
                    v.x = p[0]; v.y = p[1]; v.z = p[2]; v.w = p[3];
                }
                __builtin_nontemporal_store(v, xh4 + m);
            }
        }
    }

    // ---- p_logits / p_hard zeros ----
    if (lane < 5) extra[(size_t)5 * row + lane] = 0.f;
    if (lane == 5) extra[(size_t)5 * N + row] = 0.f;
}

// ============================================================================
// Kernel B (flat, fill-shaped): grid-stride over the float4 index space of
// coeffs. 1800 blocks x 256 thr -> 460800 threads, exactly 64 iters each
// (N*900 = 29491200 = 460800*64), no tail. Per iter: row = f/900 (magic mul),
// phase = (f%900)%3, branchless v_cndmask pattern select, nontemporal store.
// Structurally identical to the 6.26 TB/s fill except ~20 VALU + one
// L2-resident 32B wbuf read (wave's 64 lanes span <=2 rows -> broadcast-ish).
// ============================================================================
__global__ __launch_bounds__(256) void coeff_write_flat(
    const float* __restrict__ wbuf,
    float* __restrict__ coeffs,
    int total4)                       // N*900
{
    const int stride = gridDim.x * blockDim.x;        // 460800
    v4f* c4 = reinterpret_cast<v4f*>(coeffs);
    const v4f* w4 = reinterpret_cast<const v4f*>(wbuf);

    int f = blockIdx.x * blockDim.x + threadIdx.x;
    #pragma unroll 4
    for (; f < total4; f += stride) {
        const unsigned uf  = (unsigned)f;
        const unsigned row = uf / 900u;               // magic-mul by compiler
        const unsigned i   = uf - row * 900u;         // float4 index within row
        const v4f wa = w4[2u * row];                  // {w1,w2,w3,w4}
        const v4f wb = w4[2u * row + 1u];             // {w5,w6,0,0}
        const v4f P0 = wa;                            // {w1,w2,w3,w4}
        const v4f P1 = {wb.x, wb.y, wa.x, wa.y};      // {w5,w6,w1,w2}
        const v4f P2 = {wa.z, wa.w, wb.x, wb.y};      // {w3,w4,w5,w6}
        const unsigned r = i % 3u;
        v4f out = (r == 0u) ? P0 : ((r == 1u) ? P1 : P2);   // v_cndmask, no branch
        if (i <= 8u) { v4f zz = {0.f, 0.f, 0.f, 0.f}; out = zz; }  // t<6 -> 0
        __builtin_nontemporal_store(out, c4 + f);
    }
}

extern "C" void kernel_launch(void* const* d_in, const int* in_sizes, int n_in,
                              void* d_out, int out_size, void* d_ws, size_t ws_size,
                              hipStream_t stream) {
    const float* x = (const float*)d_in[0];
    const int N = in_sizes[0] / SEQ;           // 32768

    float* out    = (float*)d_out;
    float* coeffs = out;                                 // N*600*6
    float* extra  = out + (size_t)N * SEQ * PP;          // p_logits (N*5) + p_hard (N)
    float* x_hat  = extra + (size_t)N * 6;               // N*600

    float* wbuf = (float*)d_ws;                          // N*8 floats = 1 MB

    ar_solve_kernel<<<dim3(N / 4), dim3(256), 0, stream>>>(x, wbuf, extra, x_hat, N);
    coeff_write_flat<<<dim3(1800), dim3(256), 0, stream>>>(wbuf, coeffs, N * 900);
}